// Round 12
// baseline (623.518 us; speedup 1.0000x reference)
//
#include <hip/hip_runtime.h>
#include <math.h>

#define NN 50000
#define NE 800000
#define NG 64
#define NPB 224   // pooling stage-1 blocks

static __device__ __forceinline__ float lrelu(float x){ return fmaxf(x, 0.2f*x); }
static __device__ __forceinline__ unsigned fenc(float f){
  unsigned u=__float_as_uint(f); return (u&0x80000000u)? ~u : (u|0x80000000u);
}
static __device__ __forceinline__ float fdec(unsigned k){
  return (k&0x80000000u)? __uint_as_float(k&0x7FFFFFFFu) : __uint_as_float(~k);
}
static __device__ __forceinline__ unsigned short f2bf(float f){   // RNE
  unsigned u=__float_as_uint(f);
  return (unsigned short)((u + 0x7FFFu + ((u>>16)&1u))>>16);
}
static __device__ __forceinline__ float bf2f_lo(unsigned p){ return __uint_as_float(p<<16); }
static __device__ __forceinline__ float bf2f_hi(unsigned p){ return __uint_as_float(p&0xFFFF0000u); }

// ---------------- CSR build ----------------
__global__ void k_hist(const int* __restrict__ dst, int* __restrict__ hist, int E){
  for(int e=blockIdx.x*blockDim.x+threadIdx.x; e<E; e+=gridDim.x*blockDim.x)
    atomicAdd(&hist[dst[e]], 1);
}

__global__ __launch_bounds__(256) void k_bsum(const int* __restrict__ hist, int* __restrict__ bsum, int n){
  int tid=threadIdx.x; int idx=blockIdx.x*256+tid;
  int v = (idx<n)?hist[idx]:0;
  #pragma unroll
  for(int off=32;off>=1;off>>=1) v+=__shfl_xor(v,off);
  __shared__ int ws[4];
  if((tid&63)==0) ws[tid>>6]=v;
  __syncthreads();
  if(tid==0) bsum[blockIdx.x]=ws[0]+ws[1]+ws[2]+ws[3];
}

__global__ __launch_bounds__(256) void k_boff(const int* __restrict__ bsum, int* __restrict__ boff,
                                              int nb, int* __restrict__ rowp, int n){
  int tid=threadIdx.x, lane=tid&63, wv=tid>>6;
  int v = (tid<nb)?bsum[tid]:0;
  int iv=v;
  #pragma unroll
  for(int off=1;off<64;off<<=1){ int t=__shfl_up(iv,off); if(lane>=off) iv+=t; }
  __shared__ int ws[4];
  if(lane==63) ws[wv]=iv;
  __syncthreads();
  int add=0;
  for(int k=0;k<wv;k++) add+=ws[k];
  iv+=add;
  if(tid<nb) boff[tid]=iv-v;
  if(tid==255) rowp[n]=iv;     // grand total = E
}

__global__ __launch_bounds__(256) void k_scan(const int* __restrict__ hist, const int* __restrict__ boff,
                                              int* __restrict__ rowp, int* __restrict__ curp, int n){
  int tid=threadIdx.x, lane=tid&63, wv=tid>>6;
  int idx=blockIdx.x*256+tid;
  int v=(idx<n)?hist[idx]:0;
  int iv=v;
  #pragma unroll
  for(int off=1;off<64;off<<=1){ int t=__shfl_up(iv,off); if(lane>=off) iv+=t; }
  __shared__ int ws[4];
  if(lane==63) ws[wv]=iv;
  __syncthreads();
  int add=0;
  for(int k=0;k<wv;k++) add+=ws[k];
  iv+=add;
  int excl=iv-v+boff[blockIdx.x];
  if(idx<n){ rowp[idx]=excl; curp[idx]=excl; }
}

__global__ void k_scatter(const int* __restrict__ src, const int* __restrict__ dst,
                          int* __restrict__ cur, int* __restrict__ colx, int E){
  for(int e=blockIdx.x*blockDim.x+threadIdx.x; e<E; e+=gridDim.x*blockDim.x){
    int d=dst[e];
    int p=atomicAdd(&cur[d],1);
    colx[p]=src[e];
  }
}

// ------- GEMM: out[M,128] = A[M,128]@W[128,128], fused attn dot epilogue ----
// Also writes a bf16 copy of the output row (xlb) for the k_edge gather path.
template<int H>
__global__ __launch_bounds__(256) void k_gemm(const float* __restrict__ A, const float* __restrict__ W,
      const float* __restrict__ a_s, const float* __restrict__ a_d,
      float* __restrict__ out, unsigned short* __restrict__ xlb,
      float* __restrict__ asn, float* __restrict__ adn, int M){
  __shared__ float As[32][64];    // [k][row'] swizzled
  __shared__ float Bs[32][128];
  const int tid=threadIdx.x, ty=tid>>5, tx=tid&31;
  const int bm=blockIdx.x*64;
  float acc[8][4];
  #pragma unroll
  for(int r=0;r<8;r++){ acc[r][0]=0.f; acc[r][1]=0.f; acc[r][2]=0.f; acc[r][3]=0.f; }
  for(int k0=0;k0<128;k0+=32){
    #pragma unroll
    for(int i=0;i<2;i++){
      int f4=tid*2+i, row=f4>>3, kk=(f4&7)<<2;
      float4 v=make_float4(0.f,0.f,0.f,0.f);
      if(bm+row<M) v=*(const float4*)(A+(size_t)(bm+row)*128+k0+kk);
      int rs=row ^ ((kk>>3)<<3);            // (kk+j)>>3 == kk>>3 for j<4
      As[kk+0][rs]=v.x; As[kk+1][rs]=v.y; As[kk+2][rs]=v.z; As[kk+3][rs]=v.w;
    }
    #pragma unroll
    for(int i=0;i<4;i++){
      int f4=tid+i*256, kk=f4>>5, cc=(f4&31)<<2;
      *(float4*)&Bs[kk][cc] = *(const float4*)(W+(size_t)(k0+kk)*128+cc);
    }
    __syncthreads();
    #pragma unroll
    for(int k=0;k<32;k++){
      float4 b=*(const float4*)&Bs[k][tx<<2];
      int ab=(ty ^ (k>>3))<<3;
      float4 a0=*(const float4*)&As[k][ab];
      float4 a1=*(const float4*)&As[k][ab+4];
      acc[0][0]+=a0.x*b.x; acc[0][1]+=a0.x*b.y; acc[0][2]+=a0.x*b.z; acc[0][3]+=a0.x*b.w;
      acc[1][0]+=a0.y*b.x; acc[1][1]+=a0.y*b.y; acc[1][2]+=a0.y*b.z; acc[1][3]+=a0.y*b.w;
      acc[2][0]+=a0.z*b.x; acc[2][1]+=a0.z*b.y; acc[2][2]+=a0.z*b.z; acc[2][3]+=a0.z*b.w;
      acc[3][0]+=a0.w*b.x; acc[3][1]+=a0.w*b.y; acc[3][2]+=a0.w*b.z; acc[3][3]+=a0.w*b.w;
      acc[4][0]+=a1.x*b.x; acc[4][1]+=a1.x*b.y; acc[4][2]+=a1.x*b.z; acc[4][3]+=a1.x*b.w;
      acc[5][0]+=a1.y*b.x; acc[5][1]+=a1.y*b.y; acc[5][2]+=a1.y*b.z; acc[5][3]+=a1.y*b.w;
      acc[6][0]+=a1.z*b.x; acc[6][1]+=a1.z*b.y; acc[6][2]+=a1.z*b.z; acc[6][3]+=a1.z*b.w;
      acc[7][0]+=a1.w*b.x; acc[7][1]+=a1.w*b.y; acc[7][2]+=a1.w*b.z; acc[7][3]+=a1.w*b.w;
    }
    __syncthreads();
  }
  #pragma unroll
  for(int r=0;r<8;r++){
    int row=bm+ty*8+r;
    if(row<M){
      *(float4*)(out+(size_t)row*128+(tx<<2)) = make_float4(acc[r][0],acc[r][1],acc[r][2],acc[r][3]);
      uint2 pk;
      pk.x=(unsigned)f2bf(acc[r][0]) | ((unsigned)f2bf(acc[r][1])<<16);
      pk.y=(unsigned)f2bf(acc[r][2]) | ((unsigned)f2bf(acc[r][3])<<16);
      *(uint2*)(xlb+(size_t)row*128+(tx<<2)) = pk;
    }
  }
  // fused attention-dot epilogue
  float4 sa=*(const float4*)(a_s+(tx<<2));
  float4 da=*(const float4*)(a_d+(tx<<2));
  #pragma unroll
  for(int r=0;r<8;r++){
    float ps=acc[r][0]*sa.x+acc[r][1]*sa.y+acc[r][2]*sa.z+acc[r][3]*sa.w;
    float pd=acc[r][0]*da.x+acc[r][1]*da.y+acc[r][2]*da.z+acc[r][3]*da.w;
    int row=bm+ty*8+r;
    if constexpr(H==4){
      #pragma unroll
      for(int off=4;off>=1;off>>=1){ ps+=__shfl_xor(ps,off); pd+=__shfl_xor(pd,off); }
      if((tx&7)==0 && row<M){ int h0=tx>>3; asn[(size_t)row*4+h0]=ps; adn[(size_t)row*4+h0]=pd; }
    } else {
      #pragma unroll
      for(int off=16;off>=1;off>>=1){ ps+=__shfl_xor(ps,off); pd+=__shfl_xor(pd,off); }
      if(tx==0 && row<M){ asn[row]=ps; adn[row]=pd; }
    }
  }
}

// -------- GAT edge softmax + aggregation (wave per dst node) --------
// Gather: 16 edges/iteration (8 independent uint2 loads in flight per lane);
// fast __expf for all softmax exponentials. Neighbor values from bf16 copy;
// softmax math & self row stay f32.
template<int H, bool ELU>
__global__ __launch_bounds__(256) void k_edge(const int* __restrict__ rowp, const int* __restrict__ colx,
    const float* __restrict__ xl, const unsigned short* __restrict__ xlb,
    const float* __restrict__ asn, const float* __restrict__ adn,
    const float* __restrict__ bias, float* __restrict__ hout, int N){
  constexpr int C=128/H;
  __shared__ float wls[4][64*H];
  __shared__ int   sls[4][64];
  const int tid=threadIdx.x, wv=tid>>6, lane=tid&63;
  const int i=blockIdx.x*4+wv; if(i>=N) return;
  const int start=rowp[i];
  const int deg=min(max(rowp[i+1]-start,0), NE);
  const int half=lane>>5, c4=lane&31, col=c4<<2;
  const int hl = (H==4)? (c4>>3) : 0;

  float ad[H], aself[H], m[H];
  if constexpr(H==4){
    float4 t=*(const float4*)(adn+(size_t)i*4);
    ad[0]=t.x; ad[1]=t.y; ad[2]=t.z; ad[3]=t.w;
    float4 u=*(const float4*)(asn+(size_t)i*4);
    float us[4]={u.x,u.y,u.z,u.w};
    #pragma unroll
    for(int h=0;h<4;h++){ aself[h]=lrelu(us[h]+ad[h]); m[h]=aself[h]; }
  } else {
    ad[0]=adn[i]; aself[0]=lrelu(asn[i]+ad[0]); m[0]=aself[0];
  }

  // pass 1: chunk 0 alphas into registers, running per-head max
  int s0=-1; float al0[H];
  #pragma unroll
  for(int h=0;h<H;h++) al0[h]=0.f;
  if(lane<deg){
    s0=min(max(colx[start+lane],0),NN-1);
    if constexpr(H==4){
      float4 u=*(const float4*)(asn+(size_t)s0*4);
      float us[4]={u.x,u.y,u.z,u.w};
      #pragma unroll
      for(int h=0;h<4;h++){ al0[h]=lrelu(us[h]+ad[h]); m[h]=fmaxf(m[h],al0[h]); }
    } else {
      al0[0]=lrelu(asn[s0]+ad[0]); m[0]=fmaxf(m[0],al0[0]);
    }
  }
  for(int base=64;base<deg;base+=64){          // rare tail (deg>64)
    if(base+lane<deg){
      int s=min(max(colx[start+base+lane],0),NN-1);
      if constexpr(H==4){
        float4 u=*(const float4*)(asn+(size_t)s*4);
        float us[4]={u.x,u.y,u.z,u.w};
        #pragma unroll
        for(int h=0;h<4;h++) m[h]=fmaxf(m[h], lrelu(us[h]+ad[h]));
      } else {
        m[0]=fmaxf(m[0], lrelu(asn[s]+ad[0]));
      }
    }
  }
  #pragma unroll
  for(int off=32;off>=1;off>>=1){
    #pragma unroll
    for(int h=0;h<H;h++) m[h]=fmaxf(m[h], __shfl_xor(m[h],off));
  }

  float eself[H], ssum[H];
  #pragma unroll
  for(int h=0;h<H;h++){ eself[h]=__expf(aself[h]-m[h]); ssum[h]=0.f; }

  float4 acc=make_float4(0.f,0.f,0.f,0.f);
  {
    float4 xs=*(const float4*)(xl+(size_t)i*128+col);   // self row exact f32
    if(half==0){ float w=eself[hl]; acc.x=w*xs.x; acc.y=w*xs.y; acc.z=w*xs.z; acc.w=w*xs.w; }
  }

  // pass 2: weights -> LDS, gather at 16 edges / iteration (8 per half-wave)
  for(int base=0;base<deg;base+=64){
    int cnt=min(64,deg-base);
    int s=i; float ew[H];
    #pragma unroll
    for(int h=0;h<H;h++) ew[h]=0.f;
    if(lane<cnt){
      if(base==0){
        s=s0;
        #pragma unroll
        for(int h=0;h<H;h++){ ew[h]=__expf(al0[h]-m[h]); ssum[h]+=ew[h]; }
      } else {
        s=min(max(colx[start+base+lane],0),NN-1);
        if constexpr(H==4){
          float4 u=*(const float4*)(asn+(size_t)s*4);
          float us[4]={u.x,u.y,u.z,u.w};
          #pragma unroll
          for(int h=0;h<4;h++){ float a=lrelu(us[h]+ad[h]); ew[h]=__expf(a-m[h]); ssum[h]+=ew[h]; }
        } else {
          float a=lrelu(asn[s]+ad[0]); ew[0]=__expf(a-m[0]); ssum[0]+=ew[0];
        }
      }
    }
    sls[wv][lane]=s;
    #pragma unroll
    for(int h=0;h<H;h++) wls[wv][lane*H+h]=ew[h];
    // wave-synchronous LDS: prevent compiler reordering of the cross-lane reads
    __builtin_amdgcn_wave_barrier();
    for(int e0=0;e0<cnt;e0+=16){
      int   se[8]; float w8[8];
      #pragma unroll
      for(int u=0;u<8;u++){
        int eidx=e0+(half<<3)+u;          // e0<=48, +15 max -> always <64
        se[u]=sls[wv][eidx];
        w8[u]=wls[wv][eidx*H+hl];
      }
      uint2 xx[8];
      #pragma unroll
      for(int u=0;u<8;u++) xx[u]=*(const uint2*)(xlb+(size_t)se[u]*128+col);
      #pragma unroll
      for(int u=0;u<8;u++){
        acc.x+=w8[u]*bf2f_lo(xx[u].x); acc.y+=w8[u]*bf2f_hi(xx[u].x);
        acc.z+=w8[u]*bf2f_lo(xx[u].y); acc.w+=w8[u]*bf2f_hi(xx[u].y);
      }
    }
    __builtin_amdgcn_wave_barrier();
  }
  #pragma unroll
  for(int off=32;off>=1;off>>=1){
    #pragma unroll
    for(int h=0;h<H;h++) ssum[h]+=__shfl_xor(ssum[h],off);
  }
  acc.x+=__shfl_xor(acc.x,32); acc.y+=__shfl_xor(acc.y,32);
  acc.z+=__shfl_xor(acc.z,32); acc.w+=__shfl_xor(acc.w,32);
  if(half==0){
    float stot=ssum[hl]+eself[hl];
    float inv=1.f/(stot+1e-16f);
    float4 b4=*(const float4*)(bias+col);
    float ox=acc.x*inv+b4.x, oy=acc.y*inv+b4.y, oz=acc.z*inv+b4.z, ow=acc.w*inv+b4.w;
    if(ELU){
      ox = ox>0.f ? ox : expm1f(ox);
      oy = oy>0.f ? oy : expm1f(oy);
      oz = oz>0.f ? oz : expm1f(oz);
      ow = ow>0.f ? ow : expm1f(ow);
    }
    *(float4*)(hout+(size_t)i*128+col)=make_float4(ox,oy,oz,ow);
  }
}

// ------------- pooling stage 1: per-block LDS reduce -> partials -------------
__global__ __launch_bounds__(256) void k_pool1(const float* __restrict__ h, const int* __restrict__ batch,
     float* __restrict__ psum, float* __restrict__ pmax, int* __restrict__ pcnt, int N){
  __shared__ float    lsum[NG*128];
  __shared__ unsigned lmax[NG*128];
  const int tid=threadIdx.x, wv=tid>>6, lane=tid&63;
  for(int t=tid;t<NG*128;t+=256){ lsum[t]=0.f; lmax[t]=0x007FFFFFu; }  // enc(-inf)
  __syncthreads();
  int* myCnt=pcnt+blockIdx.x*NG;
  for(int i=blockIdx.x*4+wv; i<N; i+=NPB*4){
    int g=batch[i]&(NG-1);
    float2 v=*(const float2*)(h+(size_t)i*128+2*lane);
    atomicAdd(&lsum[g*128+2*lane],   v.x);
    atomicAdd(&lsum[g*128+2*lane+1], v.y);
    atomicMax(&lmax[g*128+2*lane],   fenc(v.x));
    atomicMax(&lmax[g*128+2*lane+1], fenc(v.y));
    if(lane==0) atomicAdd(&myCnt[g],1);
  }
  __syncthreads();
  for(int t=tid;t<NG*128;t+=256){
    psum[(size_t)blockIdx.x*(NG*128)+t]=lsum[t];
    pmax[(size_t)blockIdx.x*(NG*128)+t]=fdec(lmax[t]);
  }
}

// --------- classifier (folds pooling stage-2 reduction of partials) ---------
__global__ __launch_bounds__(128) void k_cls(const float* __restrict__ psum, const float* __restrict__ pmax,
    const int* __restrict__ pcnt, const float* __restrict__ cw1, const float* __restrict__ cb1,
    const float* __restrict__ cw2, const float* __restrict__ cb2, float* __restrict__ out){
  const int g=blockIdx.x, tid=threadIdx.x;
  __shared__ float gv[256];
  float s=0.f, mx=-INFINITY;
  for(int b=0;b<NPB;b++){
    s += psum[(size_t)b*(NG*128)+g*128+tid];
    mx = fmaxf(mx, pmax[(size_t)b*(NG*128)+g*128+tid]);
  }
  int cp=0;
  for(int b=tid;b<NPB;b+=128) cp+=pcnt[b*NG+g];
  #pragma unroll
  for(int off=32;off>=1;off>>=1) cp+=__shfl_xor(cp,off);
  __shared__ int cw[2];
  if((tid&63)==0) cw[tid>>6]=cp;
  __syncthreads();
  float cnt=fmaxf((float)(cw[0]+cw[1]),1.0f);
  gv[tid]=s/cnt;
  gv[128+tid]=isfinite(mx)?mx:0.f;
  __syncthreads();
  float acc=cb1[tid];
  #pragma unroll 8
  for(int k=0;k<256;k++) acc+=gv[k]*cw1[k*128+tid];
  float hrelu=fmaxf(acc,0.f);
  float p=hrelu*cw2[tid];
  #pragma unroll
  for(int off=32;off>=1;off>>=1) p+=__shfl_xor(p,off);
  __shared__ float r2[2];
  if((tid&63)==0) r2[tid>>6]=p;
  __syncthreads();
  if(tid==0) out[g]=r2[0]+r2[1]+cb2[0];
}

// ---------------- launch ----------------
extern "C" void kernel_launch(void* const* d_in, const int* in_sizes, int n_in,
                              void* d_out, int out_size, void* d_ws, size_t ws_size,
                              hipStream_t stream){
  const float* x     =(const float*)d_in[0];
  const int*   ei    =(const int*)d_in[1];
  const int*   batch =(const int*)d_in[2];
  const float* W[4]  ={(const float*)d_in[3],(const float*)d_in[7],(const float*)d_in[11],(const float*)d_in[15]};
  const float* AS[4] ={(const float*)d_in[4],(const float*)d_in[8],(const float*)d_in[12],(const float*)d_in[16]};
  const float* AD[4] ={(const float*)d_in[5],(const float*)d_in[9],(const float*)d_in[13],(const float*)d_in[17]};
  const float* BI[4] ={(const float*)d_in[6],(const float*)d_in[10],(const float*)d_in[14],(const float*)d_in[18]};
  const float* cw1=(const float*)d_in[19];
  const float* cb1=(const float*)d_in[20];
  const float* cw2=(const float*)d_in[21];
  const float* cb2=(const float*)d_in[22];
  float* out=(float*)d_out;

  const int N=NN, E=NE;
  // Workspace (~71.4 MB). xlb (bf16 gather copy, 12.8MB) overlays psum/pmax
  // (14.7MB): xlb is dead before k_pool1 writes psum/pmax. pcnt is separate
  // so its launch-start memset survives the gemm's xlb writes.
  uint8_t* w=(uint8_t*)d_ws; size_t off=0;
  auto alloc=[&](size_t bytes)->void*{ void* p=w+off; off=(off+bytes+255)&~(size_t)255; return p; };
  float*    bufH=(float*)alloc((size_t)N*128*4);   // layer output h
  float*    bufX=(float*)alloc((size_t)N*128*4);   // per-layer xl = h@W (f32)
  float*    asn =(float*)alloc((size_t)N*4*4);
  float*    adn =(float*)alloc((size_t)N*4*4);
  int*      hist=(int*)alloc((size_t)N*4);
  int*      rowp=(int*)alloc((size_t)(N+1)*4);
  int*      curp=(int*)alloc((size_t)N*4);
  int*      bsum=(int*)alloc(256*4);
  int*      boff=(int*)alloc(256*4);
  int*      colx=(int*)alloc((size_t)E*4);
  uint8_t*  povl=(uint8_t*)alloc(2*(size_t)NPB*NG*128*4);  // overlay region
  int*      pcnt=(int*)alloc((size_t)NPB*NG*4);
  unsigned short* xlb =(unsigned short*)povl;              // bf16 copy of xl (12.8MB)
  float*    psum=(float*)povl;                             // valid after last k_edge
  float*    pmax=psum+(size_t)NPB*NG*128;

  const int* esrc=ei;
  const int* edst=ei+E;
  const int nb=(N+255)/256;   // 196

  hipMemsetAsync(hist,0,(size_t)N*4,stream);
  hipMemsetAsync(pcnt,0,(size_t)NPB*NG*4,stream);
  k_hist   <<<2048,256,0,stream>>>(edst,hist,E);
  k_bsum   <<<nb,256,0,stream>>>(hist,bsum,N);
  k_boff   <<<1,256,0,stream>>>(bsum,boff,nb,rowp,N);
  k_scan   <<<nb,256,0,stream>>>(hist,boff,rowp,curp,N);
  k_scatter<<<2048,256,0,stream>>>(esrc,edst,curp,colx,E);

  const float* hin=x;
  for(int l=0;l<4;l++){
    if(l<3){
      k_gemm<4><<<(N+63)/64,256,0,stream>>>(hin,W[l],AS[l],AD[l],bufX,xlb,asn,adn,N);
      k_edge<4,true><<<(N+3)/4,256,0,stream>>>(rowp,colx,bufX,xlb,asn,adn,BI[l],bufH,N);
    } else {
      k_gemm<1><<<(N+63)/64,256,0,stream>>>(hin,W[l],AS[l],AD[l],bufX,xlb,asn,adn,N);
      k_edge<1,false><<<(N+3)/4,256,0,stream>>>(rowp,colx,bufX,xlb,asn,adn,BI[l],bufH,N);
    }
    hin=bufH;
  }

  k_pool1<<<NPB,256,0,stream>>>(bufH,batch,psum,pmax,pcnt,N);
  k_cls  <<<NG,128,0,stream>>>(psum,pmax,pcnt,cw1,cb1,cw2,cb2,out);
}

// Round 14
// 574.722 us; speedup vs baseline: 1.0849x; 1.0849x over previous
//
#include <hip/hip_runtime.h>
#include <math.h>

#define NN 50000
#define NE 800000
#define NG 64
#define NPB 224   // pooling stage-1 blocks

static __device__ __forceinline__ float lrelu(float x){ return fmaxf(x, 0.2f*x); }
static __device__ __forceinline__ unsigned fenc(float f){
  unsigned u=__float_as_uint(f); return (u&0x80000000u)? ~u : (u|0x80000000u);
}
static __device__ __forceinline__ float fdec(unsigned k){
  return (k&0x80000000u)? __uint_as_float(k&0x7FFFFFFFu) : __uint_as_float(~k);
}
static __device__ __forceinline__ unsigned short f2bf(float f){   // RNE
  unsigned u=__float_as_uint(f);
  return (unsigned short)((u + 0x7FFFu + ((u>>16)&1u))>>16);
}
static __device__ __forceinline__ float bf2f_lo(unsigned p){ return __uint_as_float(p<<16); }
static __device__ __forceinline__ float bf2f_hi(unsigned p){ return __uint_as_float(p&0xFFFF0000u); }

// ---------------- CSR build ----------------
__global__ void k_hist(const int* __restrict__ dst, int* __restrict__ hist, int E){
  for(int e=blockIdx.x*blockDim.x+threadIdx.x; e<E; e+=gridDim.x*blockDim.x)
    atomicAdd(&hist[dst[e]], 1);
}

__global__ __launch_bounds__(256) void k_bsum(const int* __restrict__ hist, int* __restrict__ bsum, int n){
  int tid=threadIdx.x; int idx=blockIdx.x*256+tid;
  int v = (idx<n)?hist[idx]:0;
  #pragma unroll
  for(int off=32;off>=1;off>>=1) v+=__shfl_xor(v,off);
  __shared__ int ws[4];
  if((tid&63)==0) ws[tid>>6]=v;
  __syncthreads();
  if(tid==0) bsum[blockIdx.x]=ws[0]+ws[1]+ws[2]+ws[3];
}

__global__ __launch_bounds__(256) void k_boff(const int* __restrict__ bsum, int* __restrict__ boff,
                                              int nb, int* __restrict__ rowp, int n){
  int tid=threadIdx.x, lane=tid&63, wv=tid>>6;
  int v = (tid<nb)?bsum[tid]:0;
  int iv=v;
  #pragma unroll
  for(int off=1;off<64;off<<=1){ int t=__shfl_up(iv,off); if(lane>=off) iv+=t; }
  __shared__ int ws[4];
  if(lane==63) ws[wv]=iv;
  __syncthreads();
  int add=0;
  for(int k=0;k<wv;k++) add+=ws[k];
  iv+=add;
  if(tid<nb) boff[tid]=iv-v;
  if(tid==255) rowp[n]=iv;     // grand total = E
}

__global__ __launch_bounds__(256) void k_scan(const int* __restrict__ hist, const int* __restrict__ boff,
                                              int* __restrict__ rowp, int* __restrict__ curp, int n){
  int tid=threadIdx.x, lane=tid&63, wv=tid>>6;
  int idx=blockIdx.x*256+tid;
  int v=(idx<n)?hist[idx]:0;
  int iv=v;
  #pragma unroll
  for(int off=1;off<64;off<<=1){ int t=__shfl_up(iv,off); if(lane>=off) iv+=t; }
  __shared__ int ws[4];
  if(lane==63) ws[wv]=iv;
  __syncthreads();
  int add=0;
  for(int k=0;k<wv;k++) add+=ws[k];
  iv+=add;
  int excl=iv-v+boff[blockIdx.x];
  if(idx<n){ rowp[idx]=excl; curp[idx]=excl; }
}

__global__ void k_scatter(const int* __restrict__ src, const int* __restrict__ dst,
                          int* __restrict__ cur, int* __restrict__ colx, int E){
  for(int e=blockIdx.x*blockDim.x+threadIdx.x; e<E; e+=gridDim.x*blockDim.x){
    int d=dst[e];
    int p=atomicAdd(&cur[d],1);
    colx[p]=src[e];
  }
}

// ------- GEMM: out[M,128] = A[M,128]@W[128,128], fused attn dot epilogue ----
// Also writes a bf16 copy of the output row (xlb) for the k_edge gather path.
template<int H>
__global__ __launch_bounds__(256) void k_gemm(const float* __restrict__ A, const float* __restrict__ W,
      const float* __restrict__ a_s, const float* __restrict__ a_d,
      float* __restrict__ out, unsigned short* __restrict__ xlb,
      float* __restrict__ asn, float* __restrict__ adn, int M){
  __shared__ float As[32][64];    // [k][row'] swizzled
  __shared__ float Bs[32][128];
  const int tid=threadIdx.x, ty=tid>>5, tx=tid&31;
  const int bm=blockIdx.x*64;
  float acc[8][4];
  #pragma unroll
  for(int r=0;r<8;r++){ acc[r][0]=0.f; acc[r][1]=0.f; acc[r][2]=0.f; acc[r][3]=0.f; }
  for(int k0=0;k0<128;k0+=32){
    #pragma unroll
    for(int i=0;i<2;i++){
      int f4=tid*2+i, row=f4>>3, kk=(f4&7)<<2;
      float4 v=make_float4(0.f,0.f,0.f,0.f);
      if(bm+row<M) v=*(const float4*)(A+(size_t)(bm+row)*128+k0+kk);
      int rs=row ^ ((kk>>3)<<3);            // (kk+j)>>3 == kk>>3 for j<4
      As[kk+0][rs]=v.x; As[kk+1][rs]=v.y; As[kk+2][rs]=v.z; As[kk+3][rs]=v.w;
    }
    #pragma unroll
    for(int i=0;i<4;i++){
      int f4=tid+i*256, kk=f4>>5, cc=(f4&31)<<2;
      *(float4*)&Bs[kk][cc] = *(const float4*)(W+(size_t)(k0+kk)*128+cc);
    }
    __syncthreads();
    #pragma unroll
    for(int k=0;k<32;k++){
      float4 b=*(const float4*)&Bs[k][tx<<2];
      int ab=(ty ^ (k>>3))<<3;
      float4 a0=*(const float4*)&As[k][ab];
      float4 a1=*(const float4*)&As[k][ab+4];
      acc[0][0]+=a0.x*b.x; acc[0][1]+=a0.x*b.y; acc[0][2]+=a0.x*b.z; acc[0][3]+=a0.x*b.w;
      acc[1][0]+=a0.y*b.x; acc[1][1]+=a0.y*b.y; acc[1][2]+=a0.y*b.z; acc[1][3]+=a0.y*b.w;
      acc[2][0]+=a0.z*b.x; acc[2][1]+=a0.z*b.y; acc[2][2]+=a0.z*b.z; acc[2][3]+=a0.z*b.w;
      acc[3][0]+=a0.w*b.x; acc[3][1]+=a0.w*b.y; acc[3][2]+=a0.w*b.z; acc[3][3]+=a0.w*b.w;
      acc[4][0]+=a1.x*b.x; acc[4][1]+=a1.x*b.y; acc[4][2]+=a1.x*b.z; acc[4][3]+=a1.x*b.w;
      acc[5][0]+=a1.y*b.x; acc[5][1]+=a1.y*b.y; acc[5][2]+=a1.y*b.z; acc[5][3]+=a1.y*b.w;
      acc[6][0]+=a1.z*b.x; acc[6][1]+=a1.z*b.y; acc[6][2]+=a1.z*b.z; acc[6][3]+=a1.z*b.w;
      acc[7][0]+=a1.w*b.x; acc[7][1]+=a1.w*b.y; acc[7][2]+=a1.w*b.z; acc[7][3]+=a1.w*b.w;
    }
    __syncthreads();
  }
  #pragma unroll
  for(int r=0;r<8;r++){
    int row=bm+ty*8+r;
    if(row<M){
      *(float4*)(out+(size_t)row*128+(tx<<2)) = make_float4(acc[r][0],acc[r][1],acc[r][2],acc[r][3]);
      uint2 pk;
      pk.x=(unsigned)f2bf(acc[r][0]) | ((unsigned)f2bf(acc[r][1])<<16);
      pk.y=(unsigned)f2bf(acc[r][2]) | ((unsigned)f2bf(acc[r][3])<<16);
      *(uint2*)(xlb+(size_t)row*128+(tx<<2)) = pk;
    }
  }
  // fused attention-dot epilogue
  float4 sa=*(const float4*)(a_s+(tx<<2));
  float4 da=*(const float4*)(a_d+(tx<<2));
  #pragma unroll
  for(int r=0;r<8;r++){
    float ps=acc[r][0]*sa.x+acc[r][1]*sa.y+acc[r][2]*sa.z+acc[r][3]*sa.w;
    float pd=acc[r][0]*da.x+acc[r][1]*da.y+acc[r][2]*da.z+acc[r][3]*da.w;
    int row=bm+ty*8+r;
    if constexpr(H==4){
      #pragma unroll
      for(int off=4;off>=1;off>>=1){ ps+=__shfl_xor(ps,off); pd+=__shfl_xor(pd,off); }
      if((tx&7)==0 && row<M){ int h0=tx>>3; asn[(size_t)row*4+h0]=ps; adn[(size_t)row*4+h0]=pd; }
    } else {
      #pragma unroll
      for(int off=16;off>=1;off>>=1){ ps+=__shfl_xor(ps,off); pd+=__shfl_xor(pd,off); }
      if(tx==0 && row<M){ asn[row]=ps; adn[row]=pd; }
    }
  }
}

// -------- GAT edge softmax + aggregation (wave per dst node) --------
// R9 structure (8 edges/iter, 4 independent uint2 loads per half-wave lane;
// VGPR ~40 keeps occupancy ~52%) + __expf hardware exponentials.
// Neighbor values from bf16 copy; softmax math & self row stay f32.
template<int H, bool ELU>
__global__ __launch_bounds__(256) void k_edge(const int* __restrict__ rowp, const int* __restrict__ colx,
    const float* __restrict__ xl, const unsigned short* __restrict__ xlb,
    const float* __restrict__ asn, const float* __restrict__ adn,
    const float* __restrict__ bias, float* __restrict__ hout, int N){
  constexpr int C=128/H;
  __shared__ float wls[4][64*H];
  __shared__ int   sls[4][64];
  const int tid=threadIdx.x, wv=tid>>6, lane=tid&63;
  const int i=blockIdx.x*4+wv; if(i>=N) return;
  const int start=rowp[i];
  const int deg=min(max(rowp[i+1]-start,0), NE);
  const int half=lane>>5, c4=lane&31, col=c4<<2;
  const int hl = (H==4)? (c4>>3) : 0;

  float ad[H], aself[H], m[H];
  if constexpr(H==4){
    float4 t=*(const float4*)(adn+(size_t)i*4);
    ad[0]=t.x; ad[1]=t.y; ad[2]=t.z; ad[3]=t.w;
    float4 u=*(const float4*)(asn+(size_t)i*4);
    float us[4]={u.x,u.y,u.z,u.w};
    #pragma unroll
    for(int h=0;h<4;h++){ aself[h]=lrelu(us[h]+ad[h]); m[h]=aself[h]; }
  } else {
    ad[0]=adn[i]; aself[0]=lrelu(asn[i]+ad[0]); m[0]=aself[0];
  }

  // pass 1: chunk 0 alphas into registers, running per-head max
  int s0=-1; float al0[H];
  #pragma unroll
  for(int h=0;h<H;h++) al0[h]=0.f;
  if(lane<deg){
    s0=min(max(colx[start+lane],0),NN-1);
    if constexpr(H==4){
      float4 u=*(const float4*)(asn+(size_t)s0*4);
      float us[4]={u.x,u.y,u.z,u.w};
      #pragma unroll
      for(int h=0;h<4;h++){ al0[h]=lrelu(us[h]+ad[h]); m[h]=fmaxf(m[h],al0[h]); }
    } else {
      al0[0]=lrelu(asn[s0]+ad[0]); m[0]=fmaxf(m[0],al0[0]);
    }
  }
  for(int base=64;base<deg;base+=64){          // rare tail (deg>64)
    if(base+lane<deg){
      int s=min(max(colx[start+base+lane],0),NN-1);
      if constexpr(H==4){
        float4 u=*(const float4*)(asn+(size_t)s*4);
        float us[4]={u.x,u.y,u.z,u.w};
        #pragma unroll
        for(int h=0;h<4;h++) m[h]=fmaxf(m[h], lrelu(us[h]+ad[h]));
      } else {
        m[0]=fmaxf(m[0], lrelu(asn[s]+ad[0]));
      }
    }
  }
  #pragma unroll
  for(int off=32;off>=1;off>>=1){
    #pragma unroll
    for(int h=0;h<H;h++) m[h]=fmaxf(m[h], __shfl_xor(m[h],off));
  }

  float eself[H], ssum[H];
  #pragma unroll
  for(int h=0;h<H;h++){ eself[h]=__expf(aself[h]-m[h]); ssum[h]=0.f; }

  float4 acc=make_float4(0.f,0.f,0.f,0.f);
  {
    float4 xs=*(const float4*)(xl+(size_t)i*128+col);   // self row exact f32
    if(half==0){ float w=eself[hl]; acc.x=w*xs.x; acc.y=w*xs.y; acc.z=w*xs.z; acc.w=w*xs.w; }
  }

  // pass 2: weights -> LDS, gather at 8 edges / iteration (4 per half-wave)
  for(int base=0;base<deg;base+=64){
    int cnt=min(64,deg-base);
    int s=i; float ew[H];
    #pragma unroll
    for(int h=0;h<H;h++) ew[h]=0.f;
    if(lane<cnt){
      if(base==0){
        s=s0;
        #pragma unroll
        for(int h=0;h<H;h++){ ew[h]=__expf(al0[h]-m[h]); ssum[h]+=ew[h]; }
      } else {
        s=min(max(colx[start+base+lane],0),NN-1);
        if constexpr(H==4){
          float4 u=*(const float4*)(asn+(size_t)s*4);
          float us[4]={u.x,u.y,u.z,u.w};
          #pragma unroll
          for(int h=0;h<4;h++){ float a=lrelu(us[h]+ad[h]); ew[h]=__expf(a-m[h]); ssum[h]+=ew[h]; }
        } else {
          float a=lrelu(asn[s]+ad[0]); ew[0]=__expf(a-m[0]); ssum[0]+=ew[0];
        }
      }
    }
    sls[wv][lane]=s;
    #pragma unroll
    for(int h=0;h<H;h++) wls[wv][lane*H+h]=ew[h];
    // wave-synchronous LDS: prevent compiler reordering of the cross-lane reads
    __builtin_amdgcn_wave_barrier();
    for(int e0=0;e0<cnt;e0+=8){
      int   se[4]; float w4[4];
      #pragma unroll
      for(int u=0;u<4;u++){
        int eidx=e0+(half<<2)+u;          // e0<=56, +7 max -> always <64
        se[u]=sls[wv][eidx];
        w4[u]=wls[wv][eidx*H+hl];
      }
      uint2 xx[4];
      #pragma unroll
      for(int u=0;u<4;u++) xx[u]=*(const uint2*)(xlb+(size_t)se[u]*128+col);
      #pragma unroll
      for(int u=0;u<4;u++){
        acc.x+=w4[u]*bf2f_lo(xx[u].x); acc.y+=w4[u]*bf2f_hi(xx[u].x);
        acc.z+=w4[u]*bf2f_lo(xx[u].y); acc.w+=w4[u]*bf2f_hi(xx[u].y);
      }
    }
    __builtin_amdgcn_wave_barrier();
  }
  #pragma unroll
  for(int off=32;off>=1;off>>=1){
    #pragma unroll
    for(int h=0;h<H;h++) ssum[h]+=__shfl_xor(ssum[h],off);
  }
  acc.x+=__shfl_xor(acc.x,32); acc.y+=__shfl_xor(acc.y,32);
  acc.z+=__shfl_xor(acc.z,32); acc.w+=__shfl_xor(acc.w,32);
  if(half==0){
    float stot=ssum[hl]+eself[hl];
    float inv=1.f/(stot+1e-16f);
    float4 b4=*(const float4*)(bias+col);
    float ox=acc.x*inv+b4.x, oy=acc.y*inv+b4.y, oz=acc.z*inv+b4.z, ow=acc.w*inv+b4.w;
    if(ELU){
      ox = ox>0.f ? ox : expm1f(ox);
      oy = oy>0.f ? oy : expm1f(oy);
      oz = oz>0.f ? oz : expm1f(oz);
      ow = ow>0.f ? ow : expm1f(ow);
    }
    *(float4*)(hout+(size_t)i*128+col)=make_float4(ox,oy,oz,ow);
  }
}

// ------------- pooling stage 1: per-block LDS reduce -> partials -------------
__global__ __launch_bounds__(256) void k_pool1(const float* __restrict__ h, const int* __restrict__ batch,
     float* __restrict__ psum, float* __restrict__ pmax, int* __restrict__ pcnt, int N){
  __shared__ float    lsum[NG*128];
  __shared__ unsigned lmax[NG*128];
  const int tid=threadIdx.x, wv=tid>>6, lane=tid&63;
  for(int t=tid;t<NG*128;t+=256){ lsum[t]=0.f; lmax[t]=0x007FFFFFu; }  // enc(-inf)
  __syncthreads();
  int* myCnt=pcnt+blockIdx.x*NG;
  for(int i=blockIdx.x*4+wv; i<N; i+=NPB*4){
    int g=batch[i]&(NG-1);
    float2 v=*(const float2*)(h+(size_t)i*128+2*lane);
    atomicAdd(&lsum[g*128+2*lane],   v.x);
    atomicAdd(&lsum[g*128+2*lane+1], v.y);
    atomicMax(&lmax[g*128+2*lane],   fenc(v.x));
    atomicMax(&lmax[g*128+2*lane+1], fenc(v.y));
    if(lane==0) atomicAdd(&myCnt[g],1);
  }
  __syncthreads();
  for(int t=tid;t<NG*128;t+=256){
    psum[(size_t)blockIdx.x*(NG*128)+t]=lsum[t];
    pmax[(size_t)blockIdx.x*(NG*128)+t]=fdec(lmax[t]);
  }
}

// --------- classifier (folds pooling stage-2 reduction of partials) ---------
__global__ __launch_bounds__(128) void k_cls(const float* __restrict__ psum, const float* __restrict__ pmax,
    const int* __restrict__ pcnt, const float* __restrict__ cw1, const float* __restrict__ cb1,
    const float* __restrict__ cw2, const float* __restrict__ cb2, float* __restrict__ out){
  const int g=blockIdx.x, tid=threadIdx.x;
  __shared__ float gv[256];
  float s=0.f, mx=-INFINITY;
  for(int b=0;b<NPB;b++){
    s += psum[(size_t)b*(NG*128)+g*128+tid];
    mx = fmaxf(mx, pmax[(size_t)b*(NG*128)+g*128+tid]);
  }
  int cp=0;
  for(int b=tid;b<NPB;b+=128) cp+=pcnt[b*NG+g];
  #pragma unroll
  for(int off=32;off>=1;off>>=1) cp+=__shfl_xor(cp,off);
  __shared__ int cw[2];
  if((tid&63)==0) cw[tid>>6]=cp;
  __syncthreads();
  float cnt=fmaxf((float)(cw[0]+cw[1]),1.0f);
  gv[tid]=s/cnt;
  gv[128+tid]=isfinite(mx)?mx:0.f;
  __syncthreads();
  float acc=cb1[tid];
  #pragma unroll 8
  for(int k=0;k<256;k++) acc+=gv[k]*cw1[k*128+tid];
  float hrelu=fmaxf(acc,0.f);
  float p=hrelu*cw2[tid];
  #pragma unroll
  for(int off=32;off>=1;off>>=1) p+=__shfl_xor(p,off);
  __shared__ float r2[2];
  if((tid&63)==0) r2[tid>>6]=p;
  __syncthreads();
  if(tid==0) out[g]=r2[0]+r2[1]+cb2[0];
}

// ---------------- launch ----------------
extern "C" void kernel_launch(void* const* d_in, const int* in_sizes, int n_in,
                              void* d_out, int out_size, void* d_ws, size_t ws_size,
                              hipStream_t stream){
  const float* x     =(const float*)d_in[0];
  const int*   ei    =(const int*)d_in[1];
  const int*   batch =(const int*)d_in[2];
  const float* W[4]  ={(const float*)d_in[3],(const float*)d_in[7],(const float*)d_in[11],(const float*)d_in[15]};
  const float* AS[4] ={(const float*)d_in[4],(const float*)d_in[8],(const float*)d_in[12],(const float*)d_in[16]};
  const float* AD[4] ={(const float*)d_in[5],(const float*)d_in[9],(const float*)d_in[13],(const float*)d_in[17]};
  const float* BI[4] ={(const float*)d_in[6],(const float*)d_in[10],(const float*)d_in[14],(const float*)d_in[18]};
  const float* cw1=(const float*)d_in[19];
  const float* cb1=(const float*)d_in[20];
  const float* cw2=(const float*)d_in[21];
  const float* cb2=(const float*)d_in[22];
  float* out=(float*)d_out;

  const int N=NN, E=NE;
  // Workspace (~71.4 MB). xlb (bf16 gather copy, 12.8MB) overlays psum/pmax
  // (14.7MB): xlb is dead before k_pool1 writes psum/pmax. pcnt is separate
  // so its launch-start memset survives the gemm's xlb writes.
  uint8_t* w=(uint8_t*)d_ws; size_t off=0;
  auto alloc=[&](size_t bytes)->void*{ void* p=w+off; off=(off+bytes+255)&~(size_t)255; return p; };
  float*    bufH=(float*)alloc((size_t)N*128*4);   // layer output h
  float*    bufX=(float*)alloc((size_t)N*128*4);   // per-layer xl = h@W (f32)
  float*    asn =(float*)alloc((size_t)N*4*4);
  float*    adn =(float*)alloc((size_t)N*4*4);
  int*      hist=(int*)alloc((size_t)N*4);
  int*      rowp=(int*)alloc((size_t)(N+1)*4);
  int*      curp=(int*)alloc((size_t)N*4);
  int*      bsum=(int*)alloc(256*4);
  int*      boff=(int*)alloc(256*4);
  int*      colx=(int*)alloc((size_t)E*4);
  uint8_t*  povl=(uint8_t*)alloc(2*(size_t)NPB*NG*128*4);  // overlay region
  int*      pcnt=(int*)alloc((size_t)NPB*NG*4);
  unsigned short* xlb =(unsigned short*)povl;              // bf16 copy of xl (12.8MB)
  float*    psum=(float*)povl;                             // valid after last k_edge
  float*    pmax=psum+(size_t)NPB*NG*128;

  const int* esrc=ei;
  const int* edst=ei+E;
  const int nb=(N+255)/256;   // 196

  hipMemsetAsync(hist,0,(size_t)N*4,stream);
  hipMemsetAsync(pcnt,0,(size_t)NPB*NG*4,stream);
  k_hist   <<<2048,256,0,stream>>>(edst,hist,E);
  k_bsum   <<<nb,256,0,stream>>>(hist,bsum,N);
  k_boff   <<<1,256,0,stream>>>(bsum,boff,nb,rowp,N);
  k_scan   <<<nb,256,0,stream>>>(hist,boff,rowp,curp,N);
  k_scatter<<<2048,256,0,stream>>>(esrc,edst,curp,colx,E);

  const float* hin=x;
  for(int l=0;l<4;l++){
    if(l<3){
      k_gemm<4><<<(N+63)/64,256,0,stream>>>(hin,W[l],AS[l],AD[l],bufX,xlb,asn,adn,N);
      k_edge<4,true><<<(N+3)/4,256,0,stream>>>(rowp,colx,bufX,xlb,asn,adn,BI[l],bufH,N);
    } else {
      k_gemm<1><<<(N+63)/64,256,0,stream>>>(hin,W[l],AS[l],AD[l],bufX,xlb,asn,adn,N);
      k_edge<1,false><<<(N+3)/4,256,0,stream>>>(rowp,colx,bufX,xlb,asn,adn,BI[l],bufH,N);
    }
    hin=bufH;
  }

  k_pool1<<<NPB,256,0,stream>>>(bufH,batch,psum,pmax,pcnt,N);
  k_cls  <<<NG,128,0,stream>>>(psum,pmax,pcnt,cw1,cb1,cw2,cb2,out);
}